// Round 1
// baseline (2022.227 us; speedup 1.0000x reference)
//
#include <hip/hip_runtime.h>

typedef unsigned short u16;
typedef __attribute__((ext_vector_type(4))) float f32x4;
typedef __attribute__((ext_vector_type(8))) __bf16 bf16x8;

__device__ __forceinline__ u16 f2bf(float f) {
  unsigned u = __float_as_uint(f);
  u += 0x7fffu + ((u >> 16) & 1u);   // round-to-nearest-even
  return (u16)(u >> 16);
}

__device__ __forceinline__ void g2l16(const void* g, void* l) {
  __builtin_amdgcn_global_load_lds(
      (const __attribute__((address_space(1))) void*)g,
      (__attribute__((address_space(3))) void*)l, 16, 0, 0);
}

// C = A @ B, A: [M][K] bf16 row-major, Bt: [N][K] bf16 row-major (i.e. B^T).
// MODE 0: Cf = fp32 out. MODE 1: Cb = bf16(silu(acc + bias[col])). MODE 2: Cb = bf16(acc).
// 128x128 tile, BK=64, 4 waves (2x2), each wave 64x64 via 4x4 MFMA 16x16x32 tiles.
// LDS staged with global_load_lds width 16; XOR chunk swizzle so ds_read_b128 frag
// reads are 2-way-bank-aliased (free per m136) without breaking the wave-uniform
// base + lane*16 LDS-destination rule of global_load_lds.
template <int MODE>
__global__ __launch_bounds__(256)
void gemm_bt(const u16* __restrict__ A, const u16* __restrict__ Bt,
             float* __restrict__ Cf, u16* __restrict__ Cb,
             const float* __restrict__ bias, int M, int N, int K)
{
  __shared__ u16 sA[128 * 64];
  __shared__ u16 sB[128 * 64];
  const int tid = threadIdx.x;
  const int lane = tid & 63;
  const int wave = tid >> 6;
  const int wm = wave >> 1;
  const int wn = wave & 1;
  const long long row0 = (long long)blockIdx.x * 128;
  const long long col0 = (long long)blockIdx.y * 128;
  const int lm = lane & 15;
  const int lq = lane >> 4;

  f32x4 acc[4][4] = {};

  for (int k0 = 0; k0 < K; k0 += 64) {
#pragma unroll
    for (int it = 0; it < 4; ++it) {
      int c = it * 256 + tid;          // chunk index 0..1023 (16B chunks)
      int r = c >> 3;                  // tile row 0..127
      int js = (c & 7) ^ (r & 7);      // swizzled source k-chunk
      const u16* ga = A + (row0 + r) * K + (k0 + js * 8);
      const u16* gb = Bt + (col0 + r) * K + (k0 + js * 8);
      int ub = (it * 256 + wave * 64) * 8;  // wave-uniform LDS base (ushort idx)
      g2l16(ga, &sA[ub]);
      g2l16(gb, &sB[ub]);
    }
    __syncthreads();
#pragma unroll
    for (int s = 0; s < 2; ++s) {
      bf16x8 af[4], bfr[4];
#pragma unroll
      for (int t = 0; t < 4; ++t) {
        int ra = wm * 64 + t * 16 + lm;
        int ja = (s * 4 + lq) ^ (ra & 7);
        af[t] = *(const bf16x8*)&sA[ra * 64 + ja * 8];
        int rb = wn * 64 + t * 16 + lm;
        int jb = (s * 4 + lq) ^ (rb & 7);
        bfr[t] = *(const bf16x8*)&sB[rb * 64 + jb * 8];
      }
#pragma unroll
      for (int i = 0; i < 4; ++i)
#pragma unroll
        for (int j = 0; j < 4; ++j)
          acc[i][j] = __builtin_amdgcn_mfma_f32_16x16x32_bf16(af[i], bfr[j], acc[i][j], 0, 0, 0);
    }
    __syncthreads();
  }

  // C/D layout (m89-verified): col = lane&15, row = (lane>>4)*4 + reg
  const int rb0 = lq * 4;
#pragma unroll
  for (int i = 0; i < 4; ++i) {
#pragma unroll
    for (int j = 0; j < 4; ++j) {
      long long grow = row0 + wm * 64 + i * 16 + rb0;
      long long gcol = col0 + wn * 64 + j * 16 + lm;
      float bcol = (MODE == 1) ? bias[gcol] : 0.f;
#pragma unroll
      for (int r = 0; r < 4; ++r) {
        long long idx = (grow + r) * N + gcol;
        float v = acc[i][j][r];
        if (MODE == 0) {
          Cf[idx] = v;
        } else if (MODE == 1) {
          float x = v + bcol;
          float sv = x / (1.f + __expf(-x));   // silu
          Cb[idx] = f2bf(sv);
        } else {
          Cb[idx] = f2bf(v);
        }
      }
    }
  }
}

// x = zc + Y + bvo ; z1 = LN(x)*g + b ; out fp32 + bf16. One wave per row (E=1024).
__global__ __launch_bounds__(256)
void ln1_kernel(const float* __restrict__ zc, const float* __restrict__ Y,
                const float* __restrict__ bvo, const float* __restrict__ g,
                const float* __restrict__ b, float* __restrict__ z1f,
                u16* __restrict__ z1b)
{
  const int row = blockIdx.x * 4 + (threadIdx.x >> 6);
  const int lane = threadIdx.x & 63;
  const long long base = (long long)row * 1024;
  const float4* pz = (const float4*)(zc + base);
  const float4* py = (const float4*)(Y + base);
  const float4* pb = (const float4*)bvo;
  float4 x[4];
  float s = 0.f, s2 = 0.f;
#pragma unroll
  for (int i = 0; i < 4; ++i) {
    int idx = lane + 64 * i;
    float4 a = pz[idx], y = py[idx], bv = pb[idx];
    float4 v;
    v.x = a.x + y.x + bv.x; v.y = a.y + y.y + bv.y;
    v.z = a.z + y.z + bv.z; v.w = a.w + y.w + bv.w;
    x[i] = v;
    s  += v.x + v.y + v.z + v.w;
    s2 += v.x * v.x + v.y * v.y + v.z * v.z + v.w * v.w;
  }
#pragma unroll
  for (int off = 32; off > 0; off >>= 1) {
    s  += __shfl_xor(s, off);
    s2 += __shfl_xor(s2, off);
  }
  const float mean = s * (1.0f / 1024.0f);
  const float var = s2 * (1.0f / 1024.0f) - mean * mean;
  const float rs = rsqrtf(var + 1e-5f);
  const float4* pg = (const float4*)g;
  const float4* pbb = (const float4*)b;
  float4* pout = (float4*)(z1f + base);
  ushort4* pob = (ushort4*)(z1b + base);
#pragma unroll
  for (int i = 0; i < 4; ++i) {
    int idx = lane + 64 * i;
    float4 gg = pg[idx], b2 = pbb[idx], v = x[i], o;
    o.x = (v.x - mean) * rs * gg.x + b2.x;
    o.y = (v.y - mean) * rs * gg.y + b2.y;
    o.z = (v.z - mean) * rs * gg.z + b2.z;
    o.w = (v.w - mean) * rs * gg.w + b2.w;
    pout[idx] = o;
    pob[idx] = make_ushort4(f2bf(o.x), f2bf(o.y), f2bf(o.z), f2bf(o.w));
  }
}

// x = z1 + F + b2c ; z = LN(x)*g + b ; zc = z + z_init.
// zout (if non-null) gets z; write_zc controls zc fp32+bf16 outputs.
__global__ __launch_bounds__(256)
void ln2_kernel(const float* __restrict__ z1, const float* __restrict__ F,
                const float* __restrict__ b2c, const float* __restrict__ g,
                const float* __restrict__ b, const float* __restrict__ zinit,
                float* __restrict__ zout, float* __restrict__ zcf,
                u16* __restrict__ zcb, int write_zc)
{
  const int row = blockIdx.x * 4 + (threadIdx.x >> 6);
  const int lane = threadIdx.x & 63;
  const long long base = (long long)row * 1024;
  const float4* pz = (const float4*)(z1 + base);
  const float4* pf = (const float4*)(F + base);
  const float4* pb = (const float4*)b2c;
  float4 x[4];
  float s = 0.f, s2 = 0.f;
#pragma unroll
  for (int i = 0; i < 4; ++i) {
    int idx = lane + 64 * i;
    float4 a = pz[idx], y = pf[idx], bv = pb[idx];
    float4 v;
    v.x = a.x + y.x + bv.x; v.y = a.y + y.y + bv.y;
    v.z = a.z + y.z + bv.z; v.w = a.w + y.w + bv.w;
    x[i] = v;
    s  += v.x + v.y + v.z + v.w;
    s2 += v.x * v.x + v.y * v.y + v.z * v.z + v.w * v.w;
  }
#pragma unroll
  for (int off = 32; off > 0; off >>= 1) {
    s  += __shfl_xor(s, off);
    s2 += __shfl_xor(s2, off);
  }
  const float mean = s * (1.0f / 1024.0f);
  const float var = s2 * (1.0f / 1024.0f) - mean * mean;
  const float rs = rsqrtf(var + 1e-5f);
  const float4* pg = (const float4*)g;
  const float4* pbb = (const float4*)b;
  const float4* pzi = (const float4*)(zinit + base);
#pragma unroll
  for (int i = 0; i < 4; ++i) {
    int idx = lane + 64 * i;
    float4 gg = pg[idx], bb = pbb[idx], v = x[i], o;
    o.x = (v.x - mean) * rs * gg.x + bb.x;
    o.y = (v.y - mean) * rs * gg.y + bb.y;
    o.z = (v.z - mean) * rs * gg.z + bb.z;
    o.w = (v.w - mean) * rs * gg.w + bb.w;
    if (zout) ((float4*)(zout + base))[idx] = o;
    if (write_zc) {
      float4 zi = pzi[idx], zc;
      zc.x = o.x + zi.x; zc.y = o.y + zi.y; zc.z = o.z + zi.z; zc.w = o.w + zi.w;
      ((float4*)(zcf + base))[idx] = zc;
      ((ushort4*)(zcb + base))[idx] = make_ushort4(f2bf(zc.x), f2bf(zc.y), f2bf(zc.z), f2bf(zc.w));
    }
  }
}

// z = z_init + Yc + ctrl_b + err @ err_W + err_b ; zc = z + z_init -> fp32 + bf16
__global__ __launch_bounds__(256)
void prologue_fin(const float* __restrict__ zinit, const float* __restrict__ Yc,
                  const float* __restrict__ ctrl_b, const float* __restrict__ err,
                  const float* __restrict__ err_W, const float* __restrict__ err_b,
                  float* __restrict__ zcf, u16* __restrict__ zcb)
{
  const int row = blockIdx.x * 4 + (threadIdx.x >> 6);
  const int lane = threadIdx.x & 63;
  const long long base = (long long)row * 1024;
  const float e0 = err[row * 2 + 0];
  const float e1 = err[row * 2 + 1];
  const float4* pz = (const float4*)(zinit + base);
  const float4* py = (const float4*)(Yc + base);
  const float4* pcb = (const float4*)ctrl_b;
  const float4* pw0 = (const float4*)err_W;
  const float4* pw1 = (const float4*)(err_W + 1024);
  const float4* peb = (const float4*)err_b;
  float4* pzc = (float4*)(zcf + base);
  ushort4* pzb = (ushort4*)(zcb + base);
#pragma unroll
  for (int i = 0; i < 4; ++i) {
    int idx = lane + 64 * i;
    float4 zi = pz[idx], y = py[idx], cb = pcb[idx], w0 = pw0[idx], w1 = pw1[idx], eb = peb[idx];
    float4 zc;
    zc.x = zi.x + y.x + cb.x + e0 * w0.x + e1 * w1.x + eb.x + zi.x;
    zc.y = zi.y + y.y + cb.y + e0 * w0.y + e1 * w1.y + eb.y + zi.y;
    zc.z = zi.z + y.z + cb.z + e0 * w0.z + e1 * w1.z + eb.z + zi.z;
    zc.w = zi.w + y.w + cb.w + e0 * w0.w + e1 * w1.w + eb.w + zi.w;
    pzc[idx] = zc;
    pzb[idx] = make_ushort4(f2bf(zc.x), f2bf(zc.y), f2bf(zc.z), f2bf(zc.w));
  }
}

// out[c][r] = bf16(in[r][c]);  in: [R][C] fp32. block (32,8), grid (C/32, R/32)
__global__ void transpose_cvt(const float* __restrict__ in, u16* __restrict__ out,
                              int R, int C)
{
  __shared__ float tile[32][33];
  const int x = blockIdx.x * 32 + threadIdx.x;
  const int y0 = blockIdx.y * 32;
#pragma unroll
  for (int i = 0; i < 32; i += 8)
    tile[threadIdx.y + i][threadIdx.x] = in[(long long)(y0 + threadIdx.y + i) * C + x];
  __syncthreads();
  const int ox = y0 + threadIdx.x;
  const int oy0 = blockIdx.x * 32;
#pragma unroll
  for (int i = 0; i < 32; i += 8)
    out[(long long)(oy0 + threadIdx.y + i) * R + ox] = f2bf(tile[threadIdx.x][threadIdx.y + i]);
}

__global__ void cvt_bf16(const float* __restrict__ in, u16* __restrict__ out, int n4)
{
  int i = blockIdx.x * 256 + threadIdx.x;
  if (i < n4) {
    float4 v = ((const float4*)in)[i];
    ((ushort4*)out)[i] = make_ushort4(f2bf(v.x), f2bf(v.y), f2bf(v.z), f2bf(v.w));
  }
}

// bvo[e] = sum_k bv[k] * Wo[k][e] + bo[e]   (E=1024)
__global__ void bias_fold(const float* __restrict__ bv, const float* __restrict__ Wo,
                          const float* __restrict__ bo, float* __restrict__ bvo)
{
  int e = blockIdx.x * 256 + threadIdx.x;
  float s = bo[e];
  for (int k = 0; k < 1024; ++k) s += bv[k] * Wo[k * 1024 + e];
  bvo[e] = s;
}

extern "C" void kernel_launch(void* const* d_in, const int* in_sizes, int n_in,
                              void* d_out, int out_size, void* d_ws, size_t ws_size,
                              hipStream_t stream)
{
  const float* z_init = (const float*)d_in[0];
  const float* ctrl   = (const float*)d_in[1];
  const float* err    = (const float*)d_in[2];
  const float* ctrl_W = (const float*)d_in[3];
  const float* ctrl_b = (const float*)d_in[4];
  const float* err_W  = (const float*)d_in[5];
  const float* err_b  = (const float*)d_in[6];
  // d_in[7]=Wq, d_in[8]=Wk, d_in[11]=bq, d_in[12]=bk: dead (softmax over 1 key == 1)
  const float* Wv    = (const float*)d_in[9];
  const float* Wo    = (const float*)d_in[10];
  const float* bv    = (const float*)d_in[13];
  const float* bo    = (const float*)d_in[14];
  const float* ln1_g = (const float*)d_in[15];
  const float* ln1_b = (const float*)d_in[16];
  const float* W1    = (const float*)d_in[17];
  const float* b1    = (const float*)d_in[18];
  const float* W2    = (const float*)d_in[19];
  const float* b2    = (const float*)d_in[20];
  const float* ln2_g = (const float*)d_in[21];
  const float* ln2_b = (const float*)d_in[22];
  // d_in[23] = num_inner_cycles = 3 (fixed launch graph)

  constexpr int B = 8192, E = 1024, H = 4096;

  char* p = (char*)d_ws;
  auto alloc = [&](size_t bytes) {
    char* r = p;
    p += (bytes + 255) & ~(size_t)255;
    return r;
  };
  float* zc_f   = (float*)alloc((size_t)B * E * 4);
  float* z1_f   = (float*)alloc((size_t)B * E * 4);
  float* tmp_f  = (float*)alloc((size_t)B * E * 4);   // Yc / Y / F (serial lifetimes)
  u16*   zc_b   = (u16*)alloc((size_t)B * E * 2);
  u16*   z1_b   = (u16*)alloc((size_t)B * E * 2);
  u16*   h_b    = (u16*)alloc((size_t)B * H * 2);
  u16*   ctrl16 = (u16*)alloc((size_t)B * 256 * 2);
  u16*   ctrlWT = (u16*)alloc((size_t)E * 256 * 2);
  u16*   Wv16   = (u16*)alloc((size_t)2 * E * E * 2);
  u16*   WoT    = (u16*)alloc((size_t)2 * E * E * 2);
  u16*   WvoT   = (u16*)alloc((size_t)2 * E * E * 2);
  u16*   W1T    = (u16*)alloc((size_t)2 * E * H * 2);
  u16*   W2T    = (u16*)alloc((size_t)2 * E * H * 2);
  float* bvo    = (float*)alloc((size_t)2 * E * 4);

  dim3 blk256(256);
  dim3 blkT(32, 8);

  // ---- per-launch weight prep (same work every call) ----
  cvt_bf16<<<(B * 256 / 4 + 255) / 256, blk256, 0, stream>>>(ctrl, ctrl16, B * 256 / 4);
  transpose_cvt<<<dim3(E / 32, 256 / 32), blkT, 0, stream>>>(ctrl_W, ctrlWT, 256, E);
  for (int i = 0; i < 2; ++i) {
    cvt_bf16<<<(E * E / 4 + 255) / 256, blk256, 0, stream>>>(Wv + (size_t)i * E * E, Wv16 + (size_t)i * E * E, E * E / 4);
    transpose_cvt<<<dim3(E / 32, E / 32), blkT, 0, stream>>>(Wo + (size_t)i * E * E, WoT + (size_t)i * E * E, E, E);
    transpose_cvt<<<dim3(H / 32, E / 32), blkT, 0, stream>>>(W1 + (size_t)i * E * H, W1T + (size_t)i * E * H, E, H);
    transpose_cvt<<<dim3(E / 32, H / 32), blkT, 0, stream>>>(W2 + (size_t)i * E * H, W2T + (size_t)i * E * H, H, E);
    bias_fold<<<E / 256, blk256, 0, stream>>>(bv + i * E, Wo + (size_t)i * E * E, bo + i * E, bvo + i * E);
  }
  // WvoT = Wo^T @ Wv^T  (A = WoT, Bt = Wv natural layout), bf16 out
  for (int i = 0; i < 2; ++i)
    gemm_bt<2><<<dim3(E / 128, E / 128), blk256, 0, stream>>>(
        WoT + (size_t)i * E * E, Wv16 + (size_t)i * E * E,
        nullptr, WvoT + (size_t)i * E * E, nullptr, E, E, E);

  // ---- prologue: z = z_init + ctrl@ctrl_W + ctrl_b + err@err_W + err_b ----
  gemm_bt<0><<<dim3(B / 128, E / 128), blk256, 0, stream>>>(ctrl16, ctrlWT, tmp_f, nullptr, nullptr, B, E, 256);
  prologue_fin<<<B / 4, blk256, 0, stream>>>(z_init, tmp_f, ctrl_b, err, err_W, err_b, zc_f, zc_b);

  // ---- 3 cycles x 2 blocks ----
  for (int it = 0; it < 6; ++it) {
    int i = it & 1;
    int last = (it == 5);
    // attn_out (pre-bias): Y = zc @ Wvo
    gemm_bt<0><<<dim3(B / 128, E / 128), blk256, 0, stream>>>(
        zc_b, WvoT + (size_t)i * E * E, tmp_f, nullptr, nullptr, B, E, E);
    ln1_kernel<<<B / 4, blk256, 0, stream>>>(zc_f, tmp_f, bvo + i * E,
        ln1_g + (size_t)i * E, ln1_b + (size_t)i * E, z1_f, z1_b);
    // h = silu(z1 @ W1 + b1), bf16
    gemm_bt<1><<<dim3(B / 128, H / 128), blk256, 0, stream>>>(
        z1_b, W1T + (size_t)i * E * H, nullptr, h_b, b1 + (size_t)i * H, B, H, E);
    // F = h @ W2
    gemm_bt<0><<<dim3(B / 128, E / 128), blk256, 0, stream>>>(
        h_b, W2T + (size_t)i * E * H, tmp_f, nullptr, nullptr, B, E, H);
    ln2_kernel<<<B / 4, blk256, 0, stream>>>(z1_f, tmp_f, b2 + (size_t)i * E,
        ln2_g + (size_t)i * E, ln2_b + (size_t)i * E, z_init,
        last ? (float*)d_out : nullptr, zc_f, zc_b, last ? 0 : 1);
  }
}

// Round 3
// 1786.268 us; speedup vs baseline: 1.1321x; 1.1321x over previous
//
#include <hip/hip_runtime.h>

typedef unsigned short u16;
typedef __attribute__((ext_vector_type(4))) float f32x4;
typedef __attribute__((ext_vector_type(8))) __bf16 bf16x8;

__device__ __forceinline__ u16 f2bf(float f) {
  unsigned u = __float_as_uint(f);
  u += 0x7fffu + ((u >> 16) & 1u);   // round-to-nearest-even
  return (u16)(u >> 16);
}
__device__ __forceinline__ float bf2f(u16 h) {
  return __uint_as_float((unsigned)h << 16);
}

__device__ __forceinline__ void g2l16(const void* g, void* l) {
  __builtin_amdgcn_global_load_lds(
      (const __attribute__((address_space(1))) void*)g,
      (__attribute__((address_space(3))) void*)l, 16, 0, 0);
}

// C = A @ B, A: [M][K] bf16 row-major, Bt: [N][K] bf16 row-major (B^T).
// MODE 0: Cf fp32. MODE 1: Cb = bf16(silu(acc + bias[col])). MODE 2: Cb = bf16(acc).
// Round-1-verified structure (m97 pattern): stage -> barrier -> compute -> barrier,
// all in one straight-line k-loop. (Round-2's cross-tile persistent variant broke
// correctness — stage issued across the epilogue CFG; do not reintroduce without
// an A=I unit test.)
template <int MODE>
__global__ __launch_bounds__(256)
void gemm_bt(const u16* __restrict__ A, const u16* __restrict__ Bt,
             float* __restrict__ Cf, u16* __restrict__ Cb,
             const float* __restrict__ bias, int M, int N, int K)
{
  __shared__ u16 sA[128 * 64];
  __shared__ u16 sB[128 * 64];
  const int tid = threadIdx.x;
  const int lane = tid & 63;
  const int wave = tid >> 6;
  const int wm = wave >> 1;
  const int wn = wave & 1;
  const long long row0 = (long long)blockIdx.x * 128;
  const long long col0 = (long long)blockIdx.y * 128;
  const int lm = lane & 15;
  const int lq = lane >> 4;

  f32x4 acc[4][4] = {};

  for (int k0 = 0; k0 < K; k0 += 64) {
#pragma unroll
    for (int it = 0; it < 4; ++it) {
      int c = it * 256 + tid;          // chunk index 0..1023 (16B chunks)
      int r = c >> 3;                  // tile row 0..127
      int js = (c & 7) ^ (r & 7);      // swizzled source k-chunk
      const u16* ga = A + (row0 + r) * K + (k0 + js * 8);
      const u16* gb = Bt + (col0 + r) * K + (k0 + js * 8);
      int ub = (it * 256 + wave * 64) * 8;  // wave-uniform LDS base (ushort idx)
      g2l16(ga, &sA[ub]);
      g2l16(gb, &sB[ub]);
    }
    __syncthreads();
#pragma unroll
    for (int s = 0; s < 2; ++s) {
      bf16x8 af[4], bfr[4];
#pragma unroll
      for (int t = 0; t < 4; ++t) {
        int ra = wm * 64 + t * 16 + lm;
        int ja = (s * 4 + lq) ^ (ra & 7);
        af[t] = *(const bf16x8*)&sA[ra * 64 + ja * 8];
        int rb = wn * 64 + t * 16 + lm;
        int jb = (s * 4 + lq) ^ (rb & 7);
        bfr[t] = *(const bf16x8*)&sB[rb * 64 + jb * 8];
      }
#pragma unroll
      for (int i = 0; i < 4; ++i)
#pragma unroll
        for (int j = 0; j < 4; ++j)
          acc[i][j] = __builtin_amdgcn_mfma_f32_16x16x32_bf16(af[i], bfr[j], acc[i][j], 0, 0, 0);
    }
    __syncthreads();
  }

  // C/D layout (m89-verified): col = lane&15, row = (lane>>4)*4 + reg
  const int rb0 = lq * 4;
#pragma unroll
  for (int i = 0; i < 4; ++i) {
#pragma unroll
    for (int j = 0; j < 4; ++j) {
      long long grow = row0 + wm * 64 + i * 16 + rb0;
      long long gcol = col0 + wn * 64 + j * 16 + lm;
      float bcol = (MODE == 1) ? bias[gcol] : 0.f;
#pragma unroll
      for (int r = 0; r < 4; ++r) {
        long long idx = (grow + r) * N + gcol;
        float v = acc[i][j][r];
        if (MODE == 0) {
          Cf[idx] = v;
        } else if (MODE == 1) {
          float x = v + bcol;
          float sv = x / (1.f + __expf(-x));   // silu
          Cb[idx] = f2bf(sv);
        } else {
          Cb[idx] = f2bf(v);
        }
      }
    }
  }
}

// x = zc + Y(bf16) + bvo ; z1 = LN(x)*g + b ; out fp32 + bf16. One wave per row.
__global__ __launch_bounds__(256)
void ln1_kernel(const float* __restrict__ zc, const u16* __restrict__ Y,
                const float* __restrict__ bvo, const float* __restrict__ g,
                const float* __restrict__ b, float* __restrict__ z1f,
                u16* __restrict__ z1b)
{
  const int row = blockIdx.x * 4 + (threadIdx.x >> 6);
  const int lane = threadIdx.x & 63;
  const long long base = (long long)row * 1024;
  const float4* pz = (const float4*)(zc + base);
  const ushort4* py = (const ushort4*)(Y + base);
  const float4* pb = (const float4*)bvo;
  float4 x[4];
  float s = 0.f, s2 = 0.f;
#pragma unroll
  for (int i = 0; i < 4; ++i) {
    int idx = lane + 64 * i;
    float4 a = pz[idx]; ushort4 yu = py[idx]; float4 bv = pb[idx];
    float4 v;
    v.x = a.x + bf2f(yu.x) + bv.x; v.y = a.y + bf2f(yu.y) + bv.y;
    v.z = a.z + bf2f(yu.z) + bv.z; v.w = a.w + bf2f(yu.w) + bv.w;
    x[i] = v;
    s  += v.x + v.y + v.z + v.w;
    s2 += v.x * v.x + v.y * v.y + v.z * v.z + v.w * v.w;
  }
#pragma unroll
  for (int off = 32; off > 0; off >>= 1) {
    s  += __shfl_xor(s, off);
    s2 += __shfl_xor(s2, off);
  }
  const float mean = s * (1.0f / 1024.0f);
  const float var = s2 * (1.0f / 1024.0f) - mean * mean;
  const float rs = rsqrtf(var + 1e-5f);
  const float4* pg = (const float4*)g;
  const float4* pbb = (const float4*)b;
  float4* pout = (float4*)(z1f + base);
  ushort4* pob = (ushort4*)(z1b + base);
#pragma unroll
  for (int i = 0; i < 4; ++i) {
    int idx = lane + 64 * i;
    float4 gg = pg[idx], b2 = pbb[idx], v = x[i], o;
    o.x = (v.x - mean) * rs * gg.x + b2.x;
    o.y = (v.y - mean) * rs * gg.y + b2.y;
    o.z = (v.z - mean) * rs * gg.z + b2.z;
    o.w = (v.w - mean) * rs * gg.w + b2.w;
    pout[idx] = o;
    pob[idx] = make_ushort4(f2bf(o.x), f2bf(o.y), f2bf(o.z), f2bf(o.w));
  }
}

// x = z1 + F(bf16) + b2c ; z = LN(x)*g + b ; zc = z + z_init (optional outputs).
__global__ __launch_bounds__(256)
void ln2_kernel(const float* __restrict__ z1, const u16* __restrict__ F,
                const float* __restrict__ b2c, const float* __restrict__ g,
                const float* __restrict__ b, const float* __restrict__ zinit,
                float* __restrict__ zout, float* __restrict__ zcf,
                u16* __restrict__ zcb, int write_zc)
{
  const int row = blockIdx.x * 4 + (threadIdx.x >> 6);
  const int lane = threadIdx.x & 63;
  const long long base = (long long)row * 1024;
  const float4* pz = (const float4*)(z1 + base);
  const ushort4* pf = (const ushort4*)(F + base);
  const float4* pb = (const float4*)b2c;
  float4 x[4];
  float s = 0.f, s2 = 0.f;
#pragma unroll
  for (int i = 0; i < 4; ++i) {
    int idx = lane + 64 * i;
    float4 a = pz[idx]; ushort4 fu = pf[idx]; float4 bv = pb[idx];
    float4 v;
    v.x = a.x + bf2f(fu.x) + bv.x; v.y = a.y + bf2f(fu.y) + bv.y;
    v.z = a.z + bf2f(fu.z) + bv.z; v.w = a.w + bf2f(fu.w) + bv.w;
    x[i] = v;
    s  += v.x + v.y + v.z + v.w;
    s2 += v.x * v.x + v.y * v.y + v.z * v.z + v.w * v.w;
  }
#pragma unroll
  for (int off = 32; off > 0; off >>= 1) {
    s  += __shfl_xor(s, off);
    s2 += __shfl_xor(s2, off);
  }
  const float mean = s * (1.0f / 1024.0f);
  const float var = s2 * (1.0f / 1024.0f) - mean * mean;
  const float rs = rsqrtf(var + 1e-5f);
  const float4* pg = (const float4*)g;
  const float4* pbb = (const float4*)b;
  const float4* pzi = (const float4*)(zinit + base);
#pragma unroll
  for (int i = 0; i < 4; ++i) {
    int idx = lane + 64 * i;
    float4 gg = pg[idx], bb = pbb[idx], v = x[i], o;
    o.x = (v.x - mean) * rs * gg.x + bb.x;
    o.y = (v.y - mean) * rs * gg.y + bb.y;
    o.z = (v.z - mean) * rs * gg.z + bb.z;
    o.w = (v.w - mean) * rs * gg.w + bb.w;
    if (zout) ((float4*)(zout + base))[idx] = o;
    if (write_zc) {
      float4 zi = pzi[idx], zc;
      zc.x = o.x + zi.x; zc.y = o.y + zi.y; zc.z = o.z + zi.z; zc.w = o.w + zi.w;
      ((float4*)(zcf + base))[idx] = zc;
      ((ushort4*)(zcb + base))[idx] = make_ushort4(f2bf(zc.x), f2bf(zc.y), f2bf(zc.z), f2bf(zc.w));
    }
  }
}

// z = z_init + Yc(bf16) + ctrl_b + err @ err_W + err_b ; zc = z + z_init
__global__ __launch_bounds__(256)
void prologue_fin(const float* __restrict__ zinit, const u16* __restrict__ Yc,
                  const float* __restrict__ ctrl_b, const float* __restrict__ err,
                  const float* __restrict__ err_W, const float* __restrict__ err_b,
                  float* __restrict__ zcf, u16* __restrict__ zcb)
{
  const int row = blockIdx.x * 4 + (threadIdx.x >> 6);
  const int lane = threadIdx.x & 63;
  const long long base = (long long)row * 1024;
  const float e0 = err[row * 2 + 0];
  const float e1 = err[row * 2 + 1];
  const float4* pz = (const float4*)(zinit + base);
  const ushort4* py = (const ushort4*)(Yc + base);
  const float4* pcb = (const float4*)ctrl_b;
  const float4* pw0 = (const float4*)err_W;
  const float4* pw1 = (const float4*)(err_W + 1024);
  const float4* peb = (const float4*)err_b;
  float4* pzc = (float4*)(zcf + base);
  ushort4* pzb = (ushort4*)(zcb + base);
#pragma unroll
  for (int i = 0; i < 4; ++i) {
    int idx = lane + 64 * i;
    float4 zi = pz[idx]; ushort4 yu = py[idx];
    float4 cb = pcb[idx], w0 = pw0[idx], w1 = pw1[idx], eb = peb[idx];
    float4 zc;
    zc.x = zi.x + bf2f(yu.x) + cb.x + e0 * w0.x + e1 * w1.x + eb.x + zi.x;
    zc.y = zi.y + bf2f(yu.y) + cb.y + e0 * w0.y + e1 * w1.y + eb.y + zi.y;
    zc.z = zi.z + bf2f(yu.z) + cb.z + e0 * w0.z + e1 * w1.z + eb.z + zi.z;
    zc.w = zi.w + bf2f(yu.w) + cb.w + e0 * w0.w + e1 * w1.w + eb.w + zi.w;
    pzc[idx] = zc;
    pzb[idx] = make_ushort4(f2bf(zc.x), f2bf(zc.y), f2bf(zc.z), f2bf(zc.w));
  }
}

// out[c][r] = bf16(in[r][c]);  in: [R][C] fp32. block (32,8), grid (C/32, R/32)
__global__ void transpose_cvt(const float* __restrict__ in, u16* __restrict__ out,
                              int R, int C)
{
  __shared__ float tile[32][33];
  const int x = blockIdx.x * 32 + threadIdx.x;
  const int y0 = blockIdx.y * 32;
#pragma unroll
  for (int i = 0; i < 32; i += 8)
    tile[threadIdx.y + i][threadIdx.x] = in[(long long)(y0 + threadIdx.y + i) * C + x];
  __syncthreads();
  const int ox = y0 + threadIdx.x;
  const int oy0 = blockIdx.x * 32;
#pragma unroll
  for (int i = 0; i < 32; i += 8)
    out[(long long)(oy0 + threadIdx.y + i) * R + ox] = f2bf(tile[threadIdx.x][threadIdx.y + i]);
}

__global__ void cvt_bf16(const float* __restrict__ in, u16* __restrict__ out, int n4)
{
  int i = blockIdx.x * 256 + threadIdx.x;
  if (i < n4) {
    float4 v = ((const float4*)in)[i];
    ((ushort4*)out)[i] = make_ushort4(f2bf(v.x), f2bf(v.y), f2bf(v.z), f2bf(v.w));
  }
}

// bvo[e] = sum_k bv[k] * Wo[k][e] + bo[e]  (E=1024); 64 cols/block, k split 4-way
__global__ void bias_fold(const float* __restrict__ bv, const float* __restrict__ Wo,
                          const float* __restrict__ bo, float* __restrict__ bvo)
{
  __shared__ float red[256];
  const int el = threadIdx.x & 63;
  const int e = blockIdx.x * 64 + el;
  const int q = threadIdx.x >> 6;
  float s = 0.f;
  for (int k = q * 256; k < q * 256 + 256; ++k) s += bv[k] * Wo[k * 1024 + e];
  red[threadIdx.x] = s;
  __syncthreads();
  if (q == 0) bvo[e] = red[el] + red[64 + el] + red[128 + el] + red[192 + el] + bo[e];
}

extern "C" void kernel_launch(void* const* d_in, const int* in_sizes, int n_in,
                              void* d_out, int out_size, void* d_ws, size_t ws_size,
                              hipStream_t stream)
{
  const float* z_init = (const float*)d_in[0];
  const float* ctrl   = (const float*)d_in[1];
  const float* err    = (const float*)d_in[2];
  const float* ctrl_W = (const float*)d_in[3];
  const float* ctrl_b = (const float*)d_in[4];
  const float* err_W  = (const float*)d_in[5];
  const float* err_b  = (const float*)d_in[6];
  // d_in[7]=Wq, d_in[8]=Wk, d_in[11]=bq, d_in[12]=bk: dead (softmax over 1 key == 1)
  const float* Wv    = (const float*)d_in[9];
  const float* Wo    = (const float*)d_in[10];
  const float* bv    = (const float*)d_in[13];
  const float* bo    = (const float*)d_in[14];
  const float* ln1_g = (const float*)d_in[15];
  const float* ln1_b = (const float*)d_in[16];
  const float* W1    = (const float*)d_in[17];
  const float* b1    = (const float*)d_in[18];
  const float* W2    = (const float*)d_in[19];
  const float* b2    = (const float*)d_in[20];
  const float* ln2_g = (const float*)d_in[21];
  const float* ln2_b = (const float*)d_in[22];

  constexpr int B = 8192, E = 1024, H = 4096;

  char* p = (char*)d_ws;
  auto alloc = [&](size_t bytes) {
    char* r = p;
    p += (bytes + 255) & ~(size_t)255;
    return r;
  };
  float* zc_f   = (float*)alloc((size_t)B * E * 4);
  float* z1_f   = (float*)alloc((size_t)B * E * 4);
  u16*   tmp_b  = (u16*)alloc((size_t)B * E * 2);   // Yc / Y / F (serial lifetimes)
  u16*   zc_b   = (u16*)alloc((size_t)B * E * 2);
  u16*   z1_b   = (u16*)alloc((size_t)B * E * 2);
  u16*   h_b    = (u16*)alloc((size_t)B * H * 2);
  u16*   ctrl16 = (u16*)alloc((size_t)B * 256 * 2);
  u16*   ctrlWT = (u16*)alloc((size_t)E * 256 * 2);
  u16*   Wv16   = (u16*)alloc((size_t)2 * E * E * 2);
  u16*   WoT    = (u16*)alloc((size_t)2 * E * E * 2);
  u16*   WvoT   = (u16*)alloc((size_t)2 * E * E * 2);
  u16*   W1T    = (u16*)alloc((size_t)2 * E * H * 2);
  u16*   W2T    = (u16*)alloc((size_t)2 * E * H * 2);
  float* bvo    = (float*)alloc((size_t)2 * E * 4);

  dim3 blk256(256);
  dim3 blkT(32, 8);

  // ---- per-launch weight prep (same work every call) ----
  cvt_bf16<<<(B * 256 / 4 + 255) / 256, blk256, 0, stream>>>(ctrl, ctrl16, B * 256 / 4);
  transpose_cvt<<<dim3(E / 32, 256 / 32), blkT, 0, stream>>>(ctrl_W, ctrlWT, 256, E);
  for (int i = 0; i < 2; ++i) {
    cvt_bf16<<<(E * E / 4 + 255) / 256, blk256, 0, stream>>>(Wv + (size_t)i * E * E, Wv16 + (size_t)i * E * E, E * E / 4);
    transpose_cvt<<<dim3(E / 32, E / 32), blkT, 0, stream>>>(Wo + (size_t)i * E * E, WoT + (size_t)i * E * E, E, E);
    transpose_cvt<<<dim3(H / 32, E / 32), blkT, 0, stream>>>(W1 + (size_t)i * E * H, W1T + (size_t)i * E * H, E, H);
    transpose_cvt<<<dim3(E / 32, H / 32), blkT, 0, stream>>>(W2 + (size_t)i * E * H, W2T + (size_t)i * E * H, H, E);
    bias_fold<<<E / 64, blk256, 0, stream>>>(bv + i * E, Wo + (size_t)i * E * E, bo + i * E, bvo + i * E);
  }
  // WvoT = Wo^T @ Wv^T  (A = WoT, Bt = Wv natural layout), bf16 out
  for (int i = 0; i < 2; ++i)
    gemm_bt<2><<<dim3(E / 128, E / 128), blk256, 0, stream>>>(
        WoT + (size_t)i * E * E, Wv16 + (size_t)i * E * E,
        nullptr, WvoT + (size_t)i * E * E, nullptr, E, E, E);

  // ---- prologue: z = z_init + ctrl@ctrl_W + ctrl_b + err@err_W + err_b ----
  gemm_bt<2><<<dim3(B / 128, E / 128), blk256, 0, stream>>>(ctrl16, ctrlWT, nullptr, tmp_b, nullptr, B, E, 256);
  prologue_fin<<<B / 4, blk256, 0, stream>>>(z_init, tmp_b, ctrl_b, err, err_W, err_b, zc_f, zc_b);

  // ---- 3 cycles x 2 blocks ----
  for (int it = 0; it < 6; ++it) {
    int i = it & 1;
    int last = (it == 5);
    // attn_out (pre-bias): Y = zc @ Wvo  (bf16 out; bvo added in ln1)
    gemm_bt<2><<<dim3(B / 128, E / 128), blk256, 0, stream>>>(
        zc_b, WvoT + (size_t)i * E * E, nullptr, tmp_b, nullptr, B, E, E);
    ln1_kernel<<<B / 4, blk256, 0, stream>>>(zc_f, tmp_b, bvo + i * E,
        ln1_g + (size_t)i * E, ln1_b + (size_t)i * E, z1_f, z1_b);
    // h = silu(z1 @ W1 + b1), bf16
    gemm_bt<1><<<dim3(B / 128, H / 128), blk256, 0, stream>>>(
        z1_b, W1T + (size_t)i * E * H, nullptr, h_b, b1 + (size_t)i * H, B, H, E);
    // F = h @ W2 (bf16 out; b2 added in ln2)
    gemm_bt<2><<<dim3(B / 128, E / 128), blk256, 0, stream>>>(
        h_b, W2T + (size_t)i * E * H, nullptr, tmp_b, nullptr, B, E, H);
    ln2_kernel<<<B / 4, blk256, 0, stream>>>(z1_f, tmp_b, b2 + (size_t)i * E,
        ln2_g + (size_t)i * E, ln2_b + (size_t)i * E, z_init,
        last ? (float*)d_out : nullptr, zc_f, zc_b, last ? 0 : 1);
  }
}

// Round 4
// 1706.913 us; speedup vs baseline: 1.1847x; 1.0465x over previous
//
#include <hip/hip_runtime.h>

typedef unsigned short u16;
typedef __attribute__((ext_vector_type(4))) float f32x4;
typedef __attribute__((ext_vector_type(8))) __bf16 bf16x8;

__device__ __forceinline__ u16 f2bf(float f) {
  unsigned u = __float_as_uint(f);
  u += 0x7fffu + ((u >> 16) & 1u);   // round-to-nearest-even
  return (u16)(u >> 16);
}
__device__ __forceinline__ float bf2f(u16 h) {
  return __uint_as_float((unsigned)h << 16);
}

__device__ __forceinline__ void g2l16(const void* g, void* l) {
  __builtin_amdgcn_global_load_lds(
      (const __attribute__((address_space(1))) void*)g,
      (__attribute__((address_space(3))) void*)l, 16, 0, 0);
}

// C = A @ B, A: [M][K] bf16 row-major, Bt: [N][K] bf16 row-major (B^T).
// MODE 0: Cf fp32. MODE 1: Cb = bf16(silu(acc + bias[col])). MODE 2: Cb = bf16(acc).
// N, K compile-time (strength-reduced addressing — runtime K cost ~75 VALU
// insts/wave/k-iter, measured VALUBusy 42% in r3). Global staging base pointers
// hoisted out of the k-loop (k-invariant; inner loop is base + k0).
// Verified m97 CFG: stage -> barrier -> compute -> barrier, straight-line k-loop.
template <int MODE, int N, int K>
__global__ __launch_bounds__(256)
void gemm_bt(const u16* __restrict__ A, const u16* __restrict__ Bt,
             float* __restrict__ Cf, u16* __restrict__ Cb,
             const float* __restrict__ bias)
{
  __shared__ u16 sA[128 * 64];
  __shared__ u16 sB[128 * 64];
  const int tid = threadIdx.x;
  const int lane = tid & 63;
  const int wave = tid >> 6;
  const int wm = wave >> 1;
  const int wn = wave & 1;
  const long long row0 = (long long)blockIdx.x * 128;
  const long long col0 = (long long)blockIdx.y * 128;
  const int lm = lane & 15;
  const int lq = lane >> 4;

  // k-invariant staging geometry: per-lane global base pointers, hoisted
  const u16* gA[4];
  const u16* gB[4];
#pragma unroll
  for (int it = 0; it < 4; ++it) {
    int c = it * 256 + tid;            // chunk index 0..1023 (16B chunks)
    int r = c >> 3;                    // tile row 0..127
    int js = (c & 7) ^ (r & 7);        // swizzled source k-chunk
    gA[it] = A + (row0 + r) * K + js * 8;
    gB[it] = Bt + (col0 + r) * K + js * 8;
  }

  f32x4 acc[4][4] = {};

  for (int k0 = 0; k0 < K; k0 += 64) {
#pragma unroll
    for (int it = 0; it < 4; ++it) {
      int ub = (it * 256 + wave * 64) * 8;  // wave-uniform LDS base (ushort idx)
      g2l16(gA[it] + k0, &sA[ub]);
      g2l16(gB[it] + k0, &sB[ub]);
    }
    __syncthreads();
#pragma unroll
    for (int s = 0; s < 2; ++s) {
      bf16x8 af[4], bfr[4];
#pragma unroll
      for (int t = 0; t < 4; ++t) {
        int ra = wm * 64 + t * 16 + lm;
        int ja = (s * 4 + lq) ^ (ra & 7);
        af[t] = *(const bf16x8*)&sA[ra * 64 + ja * 8];
        int rb = wn * 64 + t * 16 + lm;
        int jb = (s * 4 + lq) ^ (rb & 7);
        bfr[t] = *(const bf16x8*)&sB[rb * 64 + jb * 8];
      }
#pragma unroll
      for (int i = 0; i < 4; ++i)
#pragma unroll
        for (int j = 0; j < 4; ++j)
          acc[i][j] = __builtin_amdgcn_mfma_f32_16x16x32_bf16(af[i], bfr[j], acc[i][j], 0, 0, 0);
    }
    __syncthreads();
  }

  // C/D layout (m89-verified): col = lane&15, row = (lane>>4)*4 + reg
  const int rb0 = lq * 4;
#pragma unroll
  for (int i = 0; i < 4; ++i) {
#pragma unroll
    for (int j = 0; j < 4; ++j) {
      long long grow = row0 + wm * 64 + i * 16 + rb0;
      long long gcol = col0 + wn * 64 + j * 16 + lm;
      float bcol = (MODE == 1) ? bias[gcol] : 0.f;
#pragma unroll
      for (int r = 0; r < 4; ++r) {
        long long idx = (grow + r) * N + gcol;
        float v = acc[i][j][r];
        if (MODE == 0) {
          Cf[idx] = v;
        } else if (MODE == 1) {
          float x = v + bcol;
          float sv = x / (1.f + __expf(-x));   // silu
          Cb[idx] = f2bf(sv);
        } else {
          Cb[idx] = f2bf(v);
        }
      }
    }
  }
}

// x = zc + Y(bf16) + bvo ; z1 = LN(x)*g + b ; out fp32 + bf16. One wave per row.
__global__ __launch_bounds__(256)
void ln1_kernel(const float* __restrict__ zc, const u16* __restrict__ Y,
                const float* __restrict__ bvo, const float* __restrict__ g,
                const float* __restrict__ b, float* __restrict__ z1f,
                u16* __restrict__ z1b)
{
  const int row = blockIdx.x * 4 + (threadIdx.x >> 6);
  const int lane = threadIdx.x & 63;
  const long long base = (long long)row * 1024;
  const float4* pz = (const float4*)(zc + base);
  const ushort4* py = (const ushort4*)(Y + base);
  const float4* pb = (const float4*)bvo;
  float4 x[4];
  float s = 0.f, s2 = 0.f;
#pragma unroll
  for (int i = 0; i < 4; ++i) {
    int idx = lane + 64 * i;
    float4 a = pz[idx]; ushort4 yu = py[idx]; float4 bv = pb[idx];
    float4 v;
    v.x = a.x + bf2f(yu.x) + bv.x; v.y = a.y + bf2f(yu.y) + bv.y;
    v.z = a.z + bf2f(yu.z) + bv.z; v.w = a.w + bf2f(yu.w) + bv.w;
    x[i] = v;
    s  += v.x + v.y + v.z + v.w;
    s2 += v.x * v.x + v.y * v.y + v.z * v.z + v.w * v.w;
  }
#pragma unroll
  for (int off = 32; off > 0; off >>= 1) {
    s  += __shfl_xor(s, off);
    s2 += __shfl_xor(s2, off);
  }
  const float mean = s * (1.0f / 1024.0f);
  const float var = s2 * (1.0f / 1024.0f) - mean * mean;
  const float rs = rsqrtf(var + 1e-5f);
  const float4* pg = (const float4*)g;
  const float4* pbb = (const float4*)b;
  float4* pout = (float4*)(z1f + base);
  ushort4* pob = (ushort4*)(z1b + base);
#pragma unroll
  for (int i = 0; i < 4; ++i) {
    int idx = lane + 64 * i;
    float4 gg = pg[idx], b2 = pbb[idx], v = x[i], o;
    o.x = (v.x - mean) * rs * gg.x + b2.x;
    o.y = (v.y - mean) * rs * gg.y + b2.y;
    o.z = (v.z - mean) * rs * gg.z + b2.z;
    o.w = (v.w - mean) * rs * gg.w + b2.w;
    pout[idx] = o;
    pob[idx] = make_ushort4(f2bf(o.x), f2bf(o.y), f2bf(o.z), f2bf(o.w));
  }
}

// x = z1 + F(bf16) + b2c ; z = LN(x)*g + b ; zc = z + z_init (optional outputs).
__global__ __launch_bounds__(256)
void ln2_kernel(const float* __restrict__ z1, const u16* __restrict__ F,
                const float* __restrict__ b2c, const float* __restrict__ g,
                const float* __restrict__ b, const float* __restrict__ zinit,
                float* __restrict__ zout, float* __restrict__ zcf,
                u16* __restrict__ zcb, int write_zc)
{
  const int row = blockIdx.x * 4 + (threadIdx.x >> 6);
  const int lane = threadIdx.x & 63;
  const long long base = (long long)row * 1024;
  const float4* pz = (const float4*)(z1 + base);
  const ushort4* pf = (const ushort4*)(F + base);
  const float4* pb = (const float4*)b2c;
  float4 x[4];
  float s = 0.f, s2 = 0.f;
#pragma unroll
  for (int i = 0; i < 4; ++i) {
    int idx = lane + 64 * i;
    float4 a = pz[idx]; ushort4 fu = pf[idx]; float4 bv = pb[idx];
    float4 v;
    v.x = a.x + bf2f(fu.x) + bv.x; v.y = a.y + bf2f(fu.y) + bv.y;
    v.z = a.z + bf2f(fu.z) + bv.z; v.w = a.w + bf2f(fu.w) + bv.w;
    x[i] = v;
    s  += v.x + v.y + v.z + v.w;
    s2 += v.x * v.x + v.y * v.y + v.z * v.z + v.w * v.w;
  }
#pragma unroll
  for (int off = 32; off > 0; off >>= 1) {
    s  += __shfl_xor(s, off);
    s2 += __shfl_xor(s2, off);
  }
  const float mean = s * (1.0f / 1024.0f);
  const float var = s2 * (1.0f / 1024.0f) - mean * mean;
  const float rs = rsqrtf(var + 1e-5f);
  const float4* pg = (const float4*)g;
  const float4* pbb = (const float4*)b;
  const float4* pzi = (const float4*)(zinit + base);
#pragma unroll
  for (int i = 0; i < 4; ++i) {
    int idx = lane + 64 * i;
    float4 gg = pg[idx], bb = pbb[idx], v = x[i], o;
    o.x = (v.x - mean) * rs * gg.x + bb.x;
    o.y = (v.y - mean) * rs * gg.y + bb.y;
    o.z = (v.z - mean) * rs * gg.z + bb.z;
    o.w = (v.w - mean) * rs * gg.w + bb.w;
    if (zout) ((float4*)(zout + base))[idx] = o;
    if (write_zc) {
      float4 zi = pzi[idx], zc;
      zc.x = o.x + zi.x; zc.y = o.y + zi.y; zc.z = o.z + zi.z; zc.w = o.w + zi.w;
      ((float4*)(zcf + base))[idx] = zc;
      ((ushort4*)(zcb + base))[idx] = make_ushort4(f2bf(zc.x), f2bf(zc.y), f2bf(zc.z), f2bf(zc.w));
    }
  }
}

// z = z_init + Yc(bf16) + ctrl_b + err @ err_W + err_b ; zc = z + z_init
__global__ __launch_bounds__(256)
void prologue_fin(const float* __restrict__ zinit, const u16* __restrict__ Yc,
                  const float* __restrict__ ctrl_b, const float* __restrict__ err,
                  const float* __restrict__ err_W, const float* __restrict__ err_b,
                  float* __restrict__ zcf, u16* __restrict__ zcb)
{
  const int row = blockIdx.x * 4 + (threadIdx.x >> 6);
  const int lane = threadIdx.x & 63;
  const long long base = (long long)row * 1024;
  const float e0 = err[row * 2 + 0];
  const float e1 = err[row * 2 + 1];
  const float4* pz = (const float4*)(zinit + base);
  const ushort4* py = (const ushort4*)(Yc + base);
  const float4* pcb = (const float4*)ctrl_b;
  const float4* pw0 = (const float4*)err_W;
  const float4* pw1 = (const float4*)(err_W + 1024);
  const float4* peb = (const float4*)err_b;
  float4* pzc = (float4*)(zcf + base);
  ushort4* pzb = (ushort4*)(zcb + base);
#pragma unroll
  for (int i = 0; i < 4; ++i) {
    int idx = lane + 64 * i;
    float4 zi = pz[idx]; ushort4 yu = py[idx];
    float4 cb = pcb[idx], w0 = pw0[idx], w1 = pw1[idx], eb = peb[idx];
    float4 zc;
    zc.x = zi.x + bf2f(yu.x) + cb.x + e0 * w0.x + e1 * w1.x + eb.x + zi.x;
    zc.y = zi.y + bf2f(yu.y) + cb.y + e0 * w0.y + e1 * w1.y + eb.y + zi.y;
    zc.z = zi.z + bf2f(yu.z) + cb.z + e0 * w0.z + e1 * w1.z + eb.z + zi.z;
    zc.w = zi.w + bf2f(yu.w) + cb.w + e0 * w0.w + e1 * w1.w + eb.w + zi.w;
    pzc[idx] = zc;
    pzb[idx] = make_ushort4(f2bf(zc.x), f2bf(zc.y), f2bf(zc.z), f2bf(zc.w));
  }
}

// out[c][r] = bf16(in[r][c]);  in: [R][C] fp32. block (32,8), grid (C/32, R/32)
__global__ void transpose_cvt(const float* __restrict__ in, u16* __restrict__ out,
                              int R, int C)
{
  __shared__ float tile[32][33];
  const int x = blockIdx.x * 32 + threadIdx.x;
  const int y0 = blockIdx.y * 32;
#pragma unroll
  for (int i = 0; i < 32; i += 8)
    tile[threadIdx.y + i][threadIdx.x] = in[(long long)(y0 + threadIdx.y + i) * C + x];
  __syncthreads();
  const int ox = y0 + threadIdx.x;
  const int oy0 = blockIdx.x * 32;
#pragma unroll
  for (int i = 0; i < 32; i += 8)
    out[(long long)(oy0 + threadIdx.y + i) * R + ox] = f2bf(tile[threadIdx.x][threadIdx.y + i]);
}

__global__ void cvt_bf16(const float* __restrict__ in, u16* __restrict__ out, int n4)
{
  int i = blockIdx.x * 256 + threadIdx.x;
  if (i < n4) {
    float4 v = ((const float4*)in)[i];
    ((ushort4*)out)[i] = make_ushort4(f2bf(v.x), f2bf(v.y), f2bf(v.z), f2bf(v.w));
  }
}

// bvo[e] = sum_k bv[k] * Wo[k][e] + bo[e]  (E=1024); 64 cols/block, k split 4-way
__global__ void bias_fold(const float* __restrict__ bv, const float* __restrict__ Wo,
                          const float* __restrict__ bo, float* __restrict__ bvo)
{
  __shared__ float red[256];
  const int el = threadIdx.x & 63;
  const int e = blockIdx.x * 64 + el;
  const int q = threadIdx.x >> 6;
  float s = 0.f;
  for (int k = q * 256; k < q * 256 + 256; ++k) s += bv[k] * Wo[k * 1024 + e];
  red[threadIdx.x] = s;
  __syncthreads();
  if (q == 0) bvo[e] = red[el] + red[64 + el] + red[128 + el] + red[192 + el] + bo[e];
}

extern "C" void kernel_launch(void* const* d_in, const int* in_sizes, int n_in,
                              void* d_out, int out_size, void* d_ws, size_t ws_size,
                              hipStream_t stream)
{
  const float* z_init = (const float*)d_in[0];
  const float* ctrl   = (const float*)d_in[1];
  const float* err    = (const float*)d_in[2];
  const float* ctrl_W = (const float*)d_in[3];
  const float* ctrl_b = (const float*)d_in[4];
  const float* err_W  = (const float*)d_in[5];
  const float* err_b  = (const float*)d_in[6];
  // d_in[7]=Wq, d_in[8]=Wk, d_in[11]=bq, d_in[12]=bk: dead (softmax over 1 key == 1)
  const float* Wv    = (const float*)d_in[9];
  const float* Wo    = (const float*)d_in[10];
  const float* bv    = (const float*)d_in[13];
  const float* bo    = (const float*)d_in[14];
  const float* ln1_g = (const float*)d_in[15];
  const float* ln1_b = (const float*)d_in[16];
  const float* W1    = (const float*)d_in[17];
  const float* b1    = (const float*)d_in[18];
  const float* W2    = (const float*)d_in[19];
  const float* b2    = (const float*)d_in[20];
  const float* ln2_g = (const float*)d_in[21];
  const float* ln2_b = (const float*)d_in[22];

  constexpr int B = 8192, E = 1024, H = 4096;

  char* p = (char*)d_ws;
  auto alloc = [&](size_t bytes) {
    char* r = p;
    p += (bytes + 255) & ~(size_t)255;
    return r;
  };
  float* zc_f   = (float*)alloc((size_t)B * E * 4);
  float* z1_f   = (float*)alloc((size_t)B * E * 4);
  u16*   tmp_b  = (u16*)alloc((size_t)B * E * 2);   // Yc / Y / F (serial lifetimes)
  u16*   zc_b   = (u16*)alloc((size_t)B * E * 2);
  u16*   z1_b   = (u16*)alloc((size_t)B * E * 2);
  u16*   h_b    = (u16*)alloc((size_t)B * H * 2);
  u16*   ctrl16 = (u16*)alloc((size_t)B * 256 * 2);
  u16*   ctrlWT = (u16*)alloc((size_t)E * 256 * 2);
  u16*   Wv16   = (u16*)alloc((size_t)2 * E * E * 2);
  u16*   WoT    = (u16*)alloc((size_t)2 * E * E * 2);
  u16*   WvoT   = (u16*)alloc((size_t)2 * E * E * 2);
  u16*   W1T    = (u16*)alloc((size_t)2 * E * H * 2);
  u16*   W2T    = (u16*)alloc((size_t)2 * E * H * 2);
  float* bvo    = (float*)alloc((size_t)2 * E * 4);

  dim3 blk256(256);
  dim3 blkT(32, 8);

  // ---- per-launch weight prep (same work every call) ----
  cvt_bf16<<<(B * 256 / 4 + 255) / 256, blk256, 0, stream>>>(ctrl, ctrl16, B * 256 / 4);
  transpose_cvt<<<dim3(E / 32, 256 / 32), blkT, 0, stream>>>(ctrl_W, ctrlWT, 256, E);
  for (int i = 0; i < 2; ++i) {
    cvt_bf16<<<(E * E / 4 + 255) / 256, blk256, 0, stream>>>(Wv + (size_t)i * E * E, Wv16 + (size_t)i * E * E, E * E / 4);
    transpose_cvt<<<dim3(E / 32, E / 32), blkT, 0, stream>>>(Wo + (size_t)i * E * E, WoT + (size_t)i * E * E, E, E);
    transpose_cvt<<<dim3(H / 32, E / 32), blkT, 0, stream>>>(W1 + (size_t)i * E * H, W1T + (size_t)i * E * H, E, H);
    transpose_cvt<<<dim3(E / 32, H / 32), blkT, 0, stream>>>(W2 + (size_t)i * E * H, W2T + (size_t)i * E * H, H, E);
    bias_fold<<<E / 64, blk256, 0, stream>>>(bv + i * E, Wo + (size_t)i * E * E, bo + i * E, bvo + i * E);
  }
  // WvoT = Wo^T @ Wv^T  (A = WoT, Bt = Wv natural layout), bf16 out
  for (int i = 0; i < 2; ++i)
    gemm_bt<2, E, E><<<dim3(E / 128, E / 128), blk256, 0, stream>>>(
        WoT + (size_t)i * E * E, Wv16 + (size_t)i * E * E,
        nullptr, WvoT + (size_t)i * E * E, nullptr);

  // ---- prologue: z = z_init + ctrl@ctrl_W + ctrl_b + err@err_W + err_b ----
  gemm_bt<2, E, 256><<<dim3(B / 128, E / 128), blk256, 0, stream>>>(
      ctrl16, ctrlWT, nullptr, tmp_b, nullptr);
  prologue_fin<<<B / 4, blk256, 0, stream>>>(z_init, tmp_b, ctrl_b, err, err_W, err_b, zc_f, zc_b);

  // ---- 3 cycles x 2 blocks ----
  for (int it = 0; it < 6; ++it) {
    int i = it & 1;
    int last = (it == 5);
    // attn_out (pre-bias): Y = zc @ Wvo  (bf16 out; bvo added in ln1)
    gemm_bt<2, E, E><<<dim3(B / 128, E / 128), blk256, 0, stream>>>(
        zc_b, WvoT + (size_t)i * E * E, nullptr, tmp_b, nullptr);
    ln1_kernel<<<B / 4, blk256, 0, stream>>>(zc_f, tmp_b, bvo + i * E,
        ln1_g + (size_t)i * E, ln1_b + (size_t)i * E, z1_f, z1_b);
    // h = silu(z1 @ W1 + b1), bf16
    gemm_bt<1, H, E><<<dim3(B / 128, H / 128), blk256, 0, stream>>>(
        z1_b, W1T + (size_t)i * E * H, nullptr, h_b, b1 + (size_t)i * H);
    // F = h @ W2 (bf16 out; b2 added in ln2)
    gemm_bt<2, E, H><<<dim3(B / 128, E / 128), blk256, 0, stream>>>(
        h_b, W2T + (size_t)i * E * H, nullptr, tmp_b, nullptr);
    ln2_kernel<<<B / 4, blk256, 0, stream>>>(z1_f, tmp_b, b2 + (size_t)i * E,
        ln2_g + (size_t)i * E, ln2_b + (size_t)i * E, z_init,
        last ? (float*)d_out : nullptr, zc_f, zc_b, last ? 0 : 1);
  }
}

// Round 5
// 1565.304 us; speedup vs baseline: 1.2919x; 1.0905x over previous
//
#include <hip/hip_runtime.h>

typedef unsigned short u16;
typedef __attribute__((ext_vector_type(4))) float f32x4;
typedef __attribute__((ext_vector_type(8))) __bf16 bf16x8;

__device__ __forceinline__ u16 f2bf(float f) {
  unsigned u = __float_as_uint(f);
  u += 0x7fffu + ((u >> 16) & 1u);   // round-to-nearest-even
  return (u16)(u >> 16);
}
__device__ __forceinline__ float bf2f(u16 h) {
  return __uint_as_float((unsigned)h << 16);
}

__device__ __forceinline__ void g2l16(const void* g, void* l) {
  __builtin_amdgcn_global_load_lds(
      (const __attribute__((address_space(1))) void*)g,
      (__attribute__((address_space(3))) void*)l, 16, 0, 0);
}

// C = A @ B, A: [M][K] bf16 row-major, Bt: [N][K] bf16 row-major (B^T).
// MODE 0: Cf fp32. MODE 1: Cb = bf16(silu(acc + bias[col])). MODE 2: Cb = bf16(acc).
// N, K compile-time (r4: strength-reduced addressing took VALUBusy 42->38%,
// 130->99us). Verified m97 CFG: stage -> barrier -> compute -> barrier.
template <int MODE, int N, int K>
__global__ __launch_bounds__(256)
void gemm_bt(const u16* __restrict__ A, const u16* __restrict__ Bt,
             float* __restrict__ Cf, u16* __restrict__ Cb,
             const float* __restrict__ bias)
{
  __shared__ u16 sA[128 * 64];
  __shared__ u16 sB[128 * 64];
  const int tid = threadIdx.x;
  const int lane = tid & 63;
  const int wave = tid >> 6;
  const int wm = wave >> 1;
  const int wn = wave & 1;
  const long long row0 = (long long)blockIdx.x * 128;
  const long long col0 = (long long)blockIdx.y * 128;
  const int lm = lane & 15;
  const int lq = lane >> 4;

  // k-invariant staging geometry: per-lane global base pointers, hoisted
  const u16* gA[4];
  const u16* gB[4];
#pragma unroll
  for (int it = 0; it < 4; ++it) {
    int c = it * 256 + tid;            // chunk index 0..1023 (16B chunks)
    int r = c >> 3;                    // tile row 0..127
    int js = (c & 7) ^ (r & 7);        // swizzled source k-chunk
    gA[it] = A + (row0 + r) * K + js * 8;
    gB[it] = Bt + (col0 + r) * K + js * 8;
  }

  f32x4 acc[4][4] = {};

  for (int k0 = 0; k0 < K; k0 += 64) {
#pragma unroll
    for (int it = 0; it < 4; ++it) {
      int ub = (it * 256 + wave * 64) * 8;  // wave-uniform LDS base (ushort idx)
      g2l16(gA[it] + k0, &sA[ub]);
      g2l16(gB[it] + k0, &sB[ub]);
    }
    __syncthreads();
#pragma unroll
    for (int s = 0; s < 2; ++s) {
      bf16x8 af[4], bfr[4];
#pragma unroll
      for (int t = 0; t < 4; ++t) {
        int ra = wm * 64 + t * 16 + lm;
        int ja = (s * 4 + lq) ^ (ra & 7);
        af[t] = *(const bf16x8*)&sA[ra * 64 + ja * 8];
        int rb = wn * 64 + t * 16 + lm;
        int jb = (s * 4 + lq) ^ (rb & 7);
        bfr[t] = *(const bf16x8*)&sB[rb * 64 + jb * 8];
      }
#pragma unroll
      for (int i = 0; i < 4; ++i)
#pragma unroll
        for (int j = 0; j < 4; ++j)
          acc[i][j] = __builtin_amdgcn_mfma_f32_16x16x32_bf16(af[i], bfr[j], acc[i][j], 0, 0, 0);
    }
    __syncthreads();
  }

  // C/D layout (m89-verified): col = lane&15, row = (lane>>4)*4 + reg
  const int rb0 = lq * 4;
#pragma unroll
  for (int i = 0; i < 4; ++i) {
#pragma unroll
    for (int j = 0; j < 4; ++j) {
      long long grow = row0 + wm * 64 + i * 16 + rb0;
      long long gcol = col0 + wn * 64 + j * 16 + lm;
      float bcol = (MODE == 1) ? bias[gcol] : 0.f;
#pragma unroll
      for (int r = 0; r < 4; ++r) {
        long long idx = (grow + r) * N + gcol;
        float v = acc[i][j][r];
        if (MODE == 0) {
          Cf[idx] = v;
        } else if (MODE == 1) {
          float x = v + bcol;
          float sv = x / (1.f + __expf(-x));   // silu
          Cb[idx] = f2bf(sv);
        } else {
          Cb[idx] = f2bf(v);
        }
      }
    }
  }
}

// x = zc(bf16) + Y(bf16) + bvo ; z1 = LN(x)*g + b -> bf16. One wave per row (E=1024).
// r5: all-bf16 activations — fp32 residual copies dropped (48 MB/dispatch saved).
__global__ __launch_bounds__(256)
void ln1_kernel(const u16* __restrict__ zc, const u16* __restrict__ Y,
                const float* __restrict__ bvo, const float* __restrict__ g,
                const float* __restrict__ b, u16* __restrict__ z1b)
{
  const int row = blockIdx.x * 4 + (threadIdx.x >> 6);
  const int lane = threadIdx.x & 63;
  const long long base = (long long)row * 1024;
  const ushort4* pz = (const ushort4*)(zc + base);
  const ushort4* py = (const ushort4*)(Y + base);
  const float4* pb = (const float4*)bvo;
  float4 x[4];
  float s = 0.f, s2 = 0.f;
#pragma unroll
  for (int i = 0; i < 4; ++i) {
    int idx = lane + 64 * i;
    ushort4 a = pz[idx]; ushort4 yu = py[idx]; float4 bv = pb[idx];
    float4 v;
    v.x = bf2f(a.x) + bf2f(yu.x) + bv.x; v.y = bf2f(a.y) + bf2f(yu.y) + bv.y;
    v.z = bf2f(a.z) + bf2f(yu.z) + bv.z; v.w = bf2f(a.w) + bf2f(yu.w) + bv.w;
    x[i] = v;
    s  += v.x + v.y + v.z + v.w;
    s2 += v.x * v.x + v.y * v.y + v.z * v.z + v.w * v.w;
  }
#pragma unroll
  for (int off = 32; off > 0; off >>= 1) {
    s  += __shfl_xor(s, off);
    s2 += __shfl_xor(s2, off);
  }
  const float mean = s * (1.0f / 1024.0f);
  const float var = s2 * (1.0f / 1024.0f) - mean * mean;
  const float rs = rsqrtf(var + 1e-5f);
  const float4* pg = (const float4*)g;
  const float4* pbb = (const float4*)b;
  ushort4* pob = (ushort4*)(z1b + base);
#pragma unroll
  for (int i = 0; i < 4; ++i) {
    int idx = lane + 64 * i;
    float4 gg = pg[idx], b2 = pbb[idx], v = x[i], o;
    o.x = (v.x - mean) * rs * gg.x + b2.x;
    o.y = (v.y - mean) * rs * gg.y + b2.y;
    o.z = (v.z - mean) * rs * gg.z + b2.z;
    o.w = (v.w - mean) * rs * gg.w + b2.w;
    pob[idx] = make_ushort4(f2bf(o.x), f2bf(o.y), f2bf(o.z), f2bf(o.w));
  }
}

// x = z1(bf16) + F(bf16) + b2c ; z = LN(x)*g + b ;
// last iter: zout(fp32) = z ; else zc = z + z_init -> bf16.
__global__ __launch_bounds__(256)
void ln2_kernel(const u16* __restrict__ z1, const u16* __restrict__ F,
                const float* __restrict__ b2c, const float* __restrict__ g,
                const float* __restrict__ b, const float* __restrict__ zinit,
                float* __restrict__ zout, u16* __restrict__ zcb, int write_zc)
{
  const int row = blockIdx.x * 4 + (threadIdx.x >> 6);
  const int lane = threadIdx.x & 63;
  const long long base = (long long)row * 1024;
  const ushort4* pz = (const ushort4*)(z1 + base);
  const ushort4* pf = (const ushort4*)(F + base);
  const float4* pb = (const float4*)b2c;
  float4 x[4];
  float s = 0.f, s2 = 0.f;
#pragma unroll
  for (int i = 0; i < 4; ++i) {
    int idx = lane + 64 * i;
    ushort4 a = pz[idx]; ushort4 fu = pf[idx]; float4 bv = pb[idx];
    float4 v;
    v.x = bf2f(a.x) + bf2f(fu.x) + bv.x; v.y = bf2f(a.y) + bf2f(fu.y) + bv.y;
    v.z = bf2f(a.z) + bf2f(fu.z) + bv.z; v.w = bf2f(a.w) + bf2f(fu.w) + bv.w;
    x[i] = v;
    s  += v.x + v.y + v.z + v.w;
    s2 += v.x * v.x + v.y * v.y + v.z * v.z + v.w * v.w;
  }
#pragma unroll
  for (int off = 32; off > 0; off >>= 1) {
    s  += __shfl_xor(s, off);
    s2 += __shfl_xor(s2, off);
  }
  const float mean = s * (1.0f / 1024.0f);
  const float var = s2 * (1.0f / 1024.0f) - mean * mean;
  const float rs = rsqrtf(var + 1e-5f);
  const float4* pg = (const float4*)g;
  const float4* pbb = (const float4*)b;
  const float4* pzi = (const float4*)(zinit + base);
#pragma unroll
  for (int i = 0; i < 4; ++i) {
    int idx = lane + 64 * i;
    float4 gg = pg[idx], bb = pbb[idx], v = x[i], o;
    o.x = (v.x - mean) * rs * gg.x + bb.x;
    o.y = (v.y - mean) * rs * gg.y + bb.y;
    o.z = (v.z - mean) * rs * gg.z + bb.z;
    o.w = (v.w - mean) * rs * gg.w + bb.w;
    if (zout) ((float4*)(zout + base))[idx] = o;
    if (write_zc) {
      float4 zi = pzi[idx];
      ((ushort4*)(zcb + base))[idx] = make_ushort4(
          f2bf(o.x + zi.x), f2bf(o.y + zi.y), f2bf(o.z + zi.z), f2bf(o.w + zi.w));
    }
  }
}

// z = z_init + Yc(bf16) + ctrl_b + err @ err_W + err_b ; zc = z + z_init -> bf16
__global__ __launch_bounds__(256)
void prologue_fin(const float* __restrict__ zinit, const u16* __restrict__ Yc,
                  const float* __restrict__ ctrl_b, const float* __restrict__ err,
                  const float* __restrict__ err_W, const float* __restrict__ err_b,
                  u16* __restrict__ zcb)
{
  const int row = blockIdx.x * 4 + (threadIdx.x >> 6);
  const int lane = threadIdx.x & 63;
  const long long base = (long long)row * 1024;
  const float e0 = err[row * 2 + 0];
  const float e1 = err[row * 2 + 1];
  const float4* pz = (const float4*)(zinit + base);
  const ushort4* py = (const ushort4*)(Yc + base);
  const float4* pcb = (const float4*)ctrl_b;
  const float4* pw0 = (const float4*)err_W;
  const float4* pw1 = (const float4*)(err_W + 1024);
  const float4* peb = (const float4*)err_b;
  ushort4* pzb = (ushort4*)(zcb + base);
#pragma unroll
  for (int i = 0; i < 4; ++i) {
    int idx = lane + 64 * i;
    float4 zi = pz[idx]; ushort4 yu = py[idx];
    float4 cb = pcb[idx], w0 = pw0[idx], w1 = pw1[idx], eb = peb[idx];
    pzb[idx] = make_ushort4(
        f2bf(zi.x + bf2f(yu.x) + cb.x + e0 * w0.x + e1 * w1.x + eb.x + zi.x),
        f2bf(zi.y + bf2f(yu.y) + cb.y + e0 * w0.y + e1 * w1.y + eb.y + zi.y),
        f2bf(zi.z + bf2f(yu.z) + cb.z + e0 * w0.z + e1 * w1.z + eb.z + zi.z),
        f2bf(zi.w + bf2f(yu.w) + cb.w + e0 * w0.w + e1 * w1.w + eb.w + zi.w));
  }
}

// out[c][r] = bf16(in[r][c]);  in: [R][C] fp32. block (32,8), grid (C/32, R/32)
__global__ void transpose_cvt(const float* __restrict__ in, u16* __restrict__ out,
                              int R, int C)
{
  __shared__ float tile[32][33];
  const int x = blockIdx.x * 32 + threadIdx.x;
  const int y0 = blockIdx.y * 32;
#pragma unroll
  for (int i = 0; i < 32; i += 8)
    tile[threadIdx.y + i][threadIdx.x] = in[(long long)(y0 + threadIdx.y + i) * C + x];
  __syncthreads();
  const int ox = y0 + threadIdx.x;
  const int oy0 = blockIdx.x * 32;
#pragma unroll
  for (int i = 0; i < 32; i += 8)
    out[(long long)(oy0 + threadIdx.y + i) * R + ox] = f2bf(tile[threadIdx.x][threadIdx.y + i]);
}

__global__ void cvt_bf16(const float* __restrict__ in, u16* __restrict__ out, int n4)
{
  int i = blockIdx.x * 256 + threadIdx.x;
  if (i < n4) {
    float4 v = ((const float4*)in)[i];
    ((ushort4*)out)[i] = make_ushort4(f2bf(v.x), f2bf(v.y), f2bf(v.z), f2bf(v.w));
  }
}

// bvo[e] = sum_k bv[k] * Wo[k][e] + bo[e]  (E=1024); 64 cols/block, k split 4-way
__global__ void bias_fold(const float* __restrict__ bv, const float* __restrict__ Wo,
                          const float* __restrict__ bo, float* __restrict__ bvo)
{
  __shared__ float red[256];
  const int el = threadIdx.x & 63;
  const int e = blockIdx.x * 64 + el;
  const int q = threadIdx.x >> 6;
  float s = 0.f;
  for (int k = q * 256; k < q * 256 + 256; ++k) s += bv[k] * Wo[k * 1024 + e];
  red[threadIdx.x] = s;
  __syncthreads();
  if (q == 0) bvo[e] = red[el] + red[64 + el] + red[128 + el] + red[192 + el] + bo[e];
}

extern "C" void kernel_launch(void* const* d_in, const int* in_sizes, int n_in,
                              void* d_out, int out_size, void* d_ws, size_t ws_size,
                              hipStream_t stream)
{
  const float* z_init = (const float*)d_in[0];
  const float* ctrl   = (const float*)d_in[1];
  const float* err    = (const float*)d_in[2];
  const float* ctrl_W = (const float*)d_in[3];
  const float* ctrl_b = (const float*)d_in[4];
  const float* err_W  = (const float*)d_in[5];
  const float* err_b  = (const float*)d_in[6];
  // d_in[7]=Wq, d_in[8]=Wk, d_in[11]=bq, d_in[12]=bk: dead (softmax over 1 key == 1)
  const float* Wv    = (const float*)d_in[9];
  const float* Wo    = (const float*)d_in[10];
  const float* bv    = (const float*)d_in[13];
  const float* bo    = (const float*)d_in[14];
  const float* ln1_g = (const float*)d_in[15];
  const float* ln1_b = (const float*)d_in[16];
  const float* W1    = (const float*)d_in[17];
  const float* b1    = (const float*)d_in[18];
  const float* W2    = (const float*)d_in[19];
  const float* b2    = (const float*)d_in[20];
  const float* ln2_g = (const float*)d_in[21];
  const float* ln2_b = (const float*)d_in[22];

  constexpr int B = 8192, E = 1024, H = 4096;

  char* p = (char*)d_ws;
  auto alloc = [&](size_t bytes) {
    char* r = p;
    p += (bytes + 255) & ~(size_t)255;
    return r;
  };
  u16*   tmp_b  = (u16*)alloc((size_t)B * E * 2);   // Yc / Y / F (serial lifetimes)
  u16*   zc_b   = (u16*)alloc((size_t)B * E * 2);
  u16*   z1_b   = (u16*)alloc((size_t)B * E * 2);
  u16*   h_b    = (u16*)alloc((size_t)B * H * 2);
  u16*   ctrl16 = (u16*)alloc((size_t)B * 256 * 2);
  u16*   ctrlWT = (u16*)alloc((size_t)E * 256 * 2);
  u16*   Wv16   = (u16*)alloc((size_t)2 * E * E * 2);
  u16*   WoT    = (u16*)alloc((size_t)2 * E * E * 2);
  u16*   WvoT   = (u16*)alloc((size_t)2 * E * E * 2);
  u16*   W1T    = (u16*)alloc((size_t)2 * E * H * 2);
  u16*   W2T    = (u16*)alloc((size_t)2 * E * H * 2);
  float* bvo    = (float*)alloc((size_t)2 * E * 4);

  dim3 blk256(256);
  dim3 blkT(32, 8);

  // ---- per-launch weight prep (same work every call) ----
  cvt_bf16<<<(B * 256 / 4 + 255) / 256, blk256, 0, stream>>>(ctrl, ctrl16, B * 256 / 4);
  transpose_cvt<<<dim3(E / 32, 256 / 32), blkT, 0, stream>>>(ctrl_W, ctrlWT, 256, E);
  for (int i = 0; i < 2; ++i) {
    cvt_bf16<<<(E * E / 4 + 255) / 256, blk256, 0, stream>>>(Wv + (size_t)i * E * E, Wv16 + (size_t)i * E * E, E * E / 4);
    transpose_cvt<<<dim3(E / 32, E / 32), blkT, 0, stream>>>(Wo + (size_t)i * E * E, WoT + (size_t)i * E * E, E, E);
    transpose_cvt<<<dim3(H / 32, E / 32), blkT, 0, stream>>>(W1 + (size_t)i * E * H, W1T + (size_t)i * E * H, E, H);
    transpose_cvt<<<dim3(E / 32, H / 32), blkT, 0, stream>>>(W2 + (size_t)i * E * H, W2T + (size_t)i * E * H, H, E);
    bias_fold<<<E / 64, blk256, 0, stream>>>(bv + i * E, Wo + (size_t)i * E * E, bo + i * E, bvo + i * E);
  }
  // WvoT = Wo^T @ Wv^T  (A = WoT, Bt = Wv natural layout), bf16 out
  for (int i = 0; i < 2; ++i)
    gemm_bt<2, E, E><<<dim3(E / 128, E / 128), blk256, 0, stream>>>(
        WoT + (size_t)i * E * E, Wv16 + (size_t)i * E * E,
        nullptr, WvoT + (size_t)i * E * E, nullptr);

  // ---- prologue: z = z_init + ctrl@ctrl_W + ctrl_b + err@err_W + err_b ----
  gemm_bt<2, E, 256><<<dim3(B / 128, E / 128), blk256, 0, stream>>>(
      ctrl16, ctrlWT, nullptr, tmp_b, nullptr);
  prologue_fin<<<B / 4, blk256, 0, stream>>>(z_init, tmp_b, ctrl_b, err, err_W, err_b, zc_b);

  // ---- 3 cycles x 2 blocks ----
  for (int it = 0; it < 6; ++it) {
    int i = it & 1;
    int last = (it == 5);
    // attn_out (pre-bias): Y = zc @ Wvo  (bf16 out; bvo added in ln1)
    gemm_bt<2, E, E><<<dim3(B / 128, E / 128), blk256, 0, stream>>>(
        zc_b, WvoT + (size_t)i * E * E, nullptr, tmp_b, nullptr);
    ln1_kernel<<<B / 4, blk256, 0, stream>>>(zc_b, tmp_b, bvo + i * E,
        ln1_g + (size_t)i * E, ln1_b + (size_t)i * E, z1_b);
    // h = silu(z1 @ W1 + b1), bf16
    gemm_bt<1, H, E><<<dim3(B / 128, H / 128), blk256, 0, stream>>>(
        z1_b, W1T + (size_t)i * E * H, nullptr, h_b, b1 + (size_t)i * H);
    // F = h @ W2 (bf16 out; b2 added in ln2)
    gemm_bt<2, E, H><<<dim3(B / 128, E / 128), blk256, 0, stream>>>(
        h_b, W2T + (size_t)i * E * H, nullptr, tmp_b, nullptr);
    ln2_kernel<<<B / 4, blk256, 0, stream>>>(z1_b, tmp_b, b2 + (size_t)i * E,
        ln2_g + (size_t)i * E, ln2_b + (size_t)i * E, z_init,
        last ? (float*)d_out : nullptr, zc_b, last ? 0 : 1);
  }
}